// Round 7
// baseline (1934.036 us; speedup 1.0000x reference)
//
#include <hip/hip_runtime.h>

#define N_NODES 500000
#define N_EDGES 8000000
#define IN_DIM 128
#define H1 32
#define H2 16
#define NFINE 1954           // gemm1 grid: 1954*256 = 500224 >= N_NODES
#define NC 245               // coarse buckets of 2048 nodes (245*2048 = 501760)
#define CAPA 64              // stage capacity per bucket (chunk 8192, mean 33, sd 5.8)

static __device__ __forceinline__ float bf2f(unsigned short u) {
    return __uint_as_float(((unsigned int)u) << 16);
}
static __device__ __forceinline__ unsigned short f2bf(float f) {
    unsigned int u = __float_as_uint(f);
    unsigned int r = (u + 0x7fffu + ((u >> 16) & 1u)) >> 16;
    return (unsigned short)r;
}
static __device__ __forceinline__ unsigned pack2bf(float a, float b) {
    return (unsigned)f2bf(a) | ((unsigned)f2bf(b) << 16);
}
static __device__ __forceinline__ float ldf(const void* p, int i, bool isf32) {
    return isf32 ? ((const float*)p)[i] : bf2f(((const unsigned short*)p)[i]);
}

// ---- dtype sniffer ----
__global__ __launch_bounds__(64) void k_sniff(const unsigned int* __restrict__ x,
                                              int* __restrict__ flag) {
    int bad = 0;
    for (int i = threadIdx.x; i < 1024; i += 64) {
        float v = __uint_as_float((x[i] & 0xffffu) << 16);
        if (!(fabsf(v) < 1e6f)) bad = 1;
    }
    unsigned long long m = __ballot(bad);
    if (threadIdx.x == 0) *flag = (m != 0ull) ? 1 : 0;
}

// ---- coarse-bucket histogram (245 buckets of 2048 nodes) via LDS ----
__global__ __launch_bounds__(256) void k_bhist(const int* __restrict__ dst,
                                               int* __restrict__ chist) {
    __shared__ int h[256];
    int tid = threadIdx.x;
    h[tid] = 0;
    __syncthreads();
    int i = blockIdx.x * 256 + tid;
    int stride = gridDim.x * 256;
    for (int e = i; e < N_EDGES; e += stride) {
        unsigned d = (unsigned)dst[e];
        if (d < N_NODES) atomicAdd(&h[d >> 11], 1);
    }
    __syncthreads();
    if (h[tid]) atomicAdd(&chist[tid], h[tid]);
}

// ---- single-block exclusive scan over 245 coarse buckets ----
__global__ __launch_bounds__(256) void k_scanc(const int* __restrict__ chist,
                                               int* __restrict__ fbase,
                                               int* __restrict__ acur) {
    __shared__ int tmp[256];
    int tid = threadIdx.x;
    int v = (tid < NC) ? chist[tid] : 0;
    int val = v;
    tmp[tid] = val;
    __syncthreads();
    for (int o = 1; o < 256; o <<= 1) {
        int t = (tid >= o) ? tmp[tid - o] : 0;
        __syncthreads();
        val += t;
        tmp[tid] = val;
        __syncthreads();
    }
    if (tid < NC) {
        int ex = val - v;
        fbase[tid] = ex;
        acur[tid] = ex;
    }
    if (tid == NC - 1) fbase[NC] = val;   // total
}

// ---- multisplit: raw edges -> 245 coarse buckets; entry=(dst&2047)<<19 | src ----
__global__ __launch_bounds__(256) void k_scatA(const int* __restrict__ src,
                                               const int* __restrict__ dst,
                                               int* __restrict__ acur,
                                               unsigned* __restrict__ ebufA) {
    __shared__ unsigned stage[NC * CAPA];        // 62.7 KB
    __shared__ int lcnt[NC], nn[NC], soff[NC], sbase[NC];
    __shared__ int stot;
    int tid = threadIdx.x;
    int cb = blockIdx.x * 8192;                  // 977 blocks
    for (int i = tid; i < NC; i += 256) lcnt[i] = 0;
    __syncthreads();
    for (int i = 0; i < 32; ++i) {
        int e = cb + (i << 8) + tid;
        if (e < N_EDGES) {
            unsigned d = (unsigned)dst[e], s = (unsigned)src[e];
            if (d < N_NODES) {
                unsigned b = d >> 11;
                unsigned p = ((d & 2047u) << 19) | s;
                int pos = atomicAdd(&lcnt[b], 1);
                if (pos < CAPA) stage[b * CAPA + pos] = p;
                else { int slot = atomicAdd(&acur[b], 1); ebufA[slot] = p; }
            }
        }
    }
    __syncthreads();
    for (int i = tid; i < NC; i += 256) nn[i] = min(lcnt[i], CAPA);
    __syncthreads();
    if (tid == 0) {
        int r = 0;
        for (int b = 0; b < NC; ++b) { soff[b] = r; r += nn[b]; }
        stot = r;
    }
    __syncthreads();
    if (tid < NC && nn[tid] > 0) sbase[tid] = atomicAdd(&acur[tid], nn[tid]);
    __syncthreads();
    for (int i = tid; i < stot; i += 256) {      // coalesced full-line flush
        int lo = 0, hi = NC - 1;
        while (lo < hi) { int mid = (lo + hi + 1) >> 1; if (soff[mid] <= i) lo = mid; else hi = mid - 1; }
        int r = i - soff[lo];
        ebufA[sbase[lo] + r] = stage[lo * CAPA + r];
    }
}

// ---- per-node counts from coarse-binned edges (atomics hit L2-resident 8KB window) ----
__global__ __launch_bounds__(256) void k_cntL2(const unsigned* __restrict__ ebufA,
                                               const int* __restrict__ fbase,
                                               int* __restrict__ cnt) {
    int c = blockIdx.x >> 2, q = blockIdx.x & 3;
    int beg = fbase[c], end = fbase[c + 1];
    int len = end - beg;
    int qb = beg + (int)((long long)len * q >> 2);
    int qe = beg + (int)((long long)len * (q + 1) >> 2);
    for (int i = qb + threadIdx.x; i < qe; i += 256) {
        unsigned p = ebufA[i];
        int d = (c << 11) + (int)(p >> 19);
        atomicAdd(&cnt[d], 1);
    }
}

// ---- per-bucket scan of 2048 node counts -> off/cur/dinv ----
__global__ __launch_bounds__(256) void k_scanb(const int* __restrict__ cnt,
                                               const int* __restrict__ fbase,
                                               int* __restrict__ off,
                                               int* __restrict__ cur,
                                               float* __restrict__ dinv) {
    __shared__ int sums[256];
    int tid = threadIdx.x;
    int c = blockIdx.x;
    int nb = c << 11;
    int v[8];
    int loc = 0;
#pragma unroll
    for (int k = 0; k < 8; ++k) { v[k] = cnt[nb + tid * 8 + k]; loc += v[k]; }
    sums[tid] = loc;
    __syncthreads();
    int val = loc;
    for (int o = 1; o < 256; o <<= 1) {
        int t = (tid >= o) ? sums[tid - o] : 0;
        __syncthreads();
        val += t;
        sums[tid] = val;
        __syncthreads();
    }
    int run = fbase[c] + val - loc;              // exclusive prefix
#pragma unroll
    for (int k = 0; k < 8; ++k) {
        int d = nb + tid * 8 + k;
        off[d] = run;
        cur[d] = run;
        dinv[d] = rsqrtf((float)v[k] + 1.0f);
        run += v[k];
    }
    if (c == NC - 1 && tid == 255) off[NC * 2048] = run;   // global end sentinel
}

// ---- csr fill: slot atomics + stores land in per-bucket L2-resident windows ----
__global__ __launch_bounds__(256) void k_fill2(const unsigned* __restrict__ ebufA,
                                               const int* __restrict__ fbase,
                                               int* __restrict__ cur,
                                               int* __restrict__ csr) {
    int c = blockIdx.x >> 2, q = blockIdx.x & 3;
    int beg = fbase[c], end = fbase[c + 1];
    int len = end - beg;
    int qb = beg + (int)((long long)len * q >> 2);
    int qe = beg + (int)((long long)len * (q + 1) >> 2);
    for (int i = qb + threadIdx.x; i < qe; i += 256) {
        unsigned p = ebufA[i];
        int d = (c << 11) + (int)(p >> 19);
        int slot = atomicAdd(&cur[d], 1);
        csr[slot] = (int)(p & 0x7FFFFu);
    }
}

// ---- y1 = (x @ W1) * dinv  -> bf16 rows (32 x bf16 = 64B) ----
__global__ __launch_bounds__(256) void k_gemm1(const void* __restrict__ x,
                                               const void* __restrict__ w1,
                                               const float* __restrict__ dinv,
                                               unsigned* __restrict__ y1b,
                                               const int* __restrict__ flag) {
    __shared__ float wlds[IN_DIM * H1];
    const bool isf32 = (*flag != 0);
    for (int i = threadIdx.x; i < IN_DIM * H1; i += 256) wlds[i] = ldf(w1, i, isf32);
    __syncthreads();
    int node = blockIdx.x * 256 + threadIdx.x;
    if (node >= N_NODES) return;
    float acc[H1];
#pragma unroll
    for (int j = 0; j < H1; ++j) acc[j] = 0.f;
    if (isf32) {
        const float4* xr = reinterpret_cast<const float4*>((const float*)x + (size_t)node * IN_DIM);
#pragma unroll
        for (int kk = 0; kk < IN_DIM / 4; ++kk) {
            float4 v = xr[kk];
            float xe[4] = {v.x, v.y, v.z, v.w};
#pragma unroll
            for (int p = 0; p < 4; ++p) {
                const float* wr = &wlds[(kk * 4 + p) * H1];
#pragma unroll
                for (int j = 0; j < H1; ++j) acc[j] += xe[p] * wr[j];
            }
        }
    } else {
        const uint4* xr = reinterpret_cast<const uint4*>((const unsigned short*)x + (size_t)node * IN_DIM);
#pragma unroll
        for (int kk = 0; kk < IN_DIM / 8; ++kk) {
            uint4 xv = xr[kk];
            unsigned uu[4] = {xv.x, xv.y, xv.z, xv.w};
#pragma unroll
            for (int p = 0; p < 4; ++p) {
                float xlo = __uint_as_float(uu[p] << 16);
                float xhi = __uint_as_float(uu[p] & 0xffff0000u);
                const float* w0 = &wlds[(kk * 8 + p * 2) * H1];
                const float* w1r = w0 + H1;
#pragma unroll
                for (int j = 0; j < H1; ++j) acc[j] += xlo * w0[j];
#pragma unroll
                for (int j = 0; j < H1; ++j) acc[j] += xhi * w1r[j];
            }
        }
    }
    float s = dinv[node];
    unsigned o[16];
#pragma unroll
    for (int q = 0; q < 16; ++q) o[q] = pack2bf(acc[2*q] * s, acc[2*q+1] * s);
    uint4* op = reinterpret_cast<uint4*>(y1b + (size_t)node * 16);
#pragma unroll
    for (int r = 0; r < 4; ++r) op[r] = make_uint4(o[4*r], o[4*r+1], o[4*r+2], o[4*r+3]);
}

// ---- pull layer 1: 16 lanes/node, ILP-4 row gathers, fused relu+GEMM2 ----
__global__ __launch_bounds__(256) void k_pull1(const int* __restrict__ off,
                                               const int* __restrict__ csr,
                                               const unsigned* __restrict__ y1b,
                                               const float* __restrict__ dinv,
                                               const void* __restrict__ b1,
                                               const void* __restrict__ w2,
                                               unsigned* __restrict__ y2b,
                                               const int* __restrict__ flag) {
    __shared__ float w2l[H1 * H2];
    __shared__ float b1l[H1];
    __shared__ float hbuf[512];
    const bool isf32 = (*flag != 0);
    int tid = threadIdx.x;
    for (int i = tid; i < H1 * H2; i += 256) w2l[i] = ldf(w2, i, isf32);
    if (tid < H1) b1l[tid] = ldf(b1, tid, isf32);
    __syncthreads();

    const int r = tid & 15;
    const int node = blockIdx.x * 16 + (tid >> 4);   // 31250*16 == 500000

    float a0 = 0.f, a1 = 0.f;
    const int beg = off[node], end = off[node + 1];
    int j = beg;
    for (; j + 4 <= end; j += 4) {
        int s0 = csr[j], s1 = csr[j + 1], s2 = csr[j + 2], s3 = csr[j + 3];
        unsigned u0 = y1b[(size_t)s0 * 16 + r];
        unsigned u1 = y1b[(size_t)s1 * 16 + r];
        unsigned u2 = y1b[(size_t)s2 * 16 + r];
        unsigned u3 = y1b[(size_t)s3 * 16 + r];
        a0 += __uint_as_float(u0 << 16) + __uint_as_float(u1 << 16)
            + __uint_as_float(u2 << 16) + __uint_as_float(u3 << 16);
        a1 += __uint_as_float(u0 & 0xffff0000u) + __uint_as_float(u1 & 0xffff0000u)
            + __uint_as_float(u2 & 0xffff0000u) + __uint_as_float(u3 & 0xffff0000u);
    }
    for (; j < end; ++j) {
        unsigned u = y1b[(size_t)csr[j] * 16 + r];
        a0 += __uint_as_float(u << 16);
        a1 += __uint_as_float(u & 0xffff0000u);
    }
    float sc = dinv[node];
    unsigned su = y1b[(size_t)node * 16 + r];        // self term (pre-scaled)
    a0 += __uint_as_float(su << 16);
    a1 += __uint_as_float(su & 0xffff0000u);
    float h0 = sc * a0 + b1l[2 * r];
    float h1 = sc * a1 + b1l[2 * r + 1];
    h0 = h0 > 0.f ? h0 : 0.f;
    h1 = h1 > 0.f ? h1 : 0.f;
    hbuf[tid * 2] = h0;
    hbuf[tid * 2 + 1] = h1;                          // same-wave readers only
    const float* hr = &hbuf[(tid & ~15) * 2];
    float a2 = 0.f;
#pragma unroll
    for (int k = 0; k < H1; ++k) a2 += hr[k] * w2l[k * H2 + r];
    a2 *= sc;
    int gwb = (tid & 63) & ~15;                      // wave-lane group base
    float v0 = __shfl(a2, (gwb + 2 * r) & 63, 64);
    float v1 = __shfl(a2, (gwb + 2 * r + 1) & 63, 64);
    if (r < 8) y2b[(size_t)node * 8 + r] = pack2bf(v0, v1);
}

// ---- pull layer 2: 8 lanes/node, ILP-4, fused relu+FC+log_softmax ----
__global__ __launch_bounds__(256) void k_pull2(const int* __restrict__ off,
                                               const int* __restrict__ csr,
                                               const unsigned* __restrict__ y2b,
                                               const float* __restrict__ dinv,
                                               const void* __restrict__ b2,
                                               const void* __restrict__ wfc,
                                               const void* __restrict__ bfc,
                                               void* __restrict__ out,
                                               const int* __restrict__ flag) {
    __shared__ float wl[H2 * 2];
    __shared__ float b2l[H2];
    __shared__ float bfl[2];
    const bool isf32 = (*flag != 0);
    int tid = threadIdx.x;
    if (tid < H2 * 2) wl[tid] = ldf(wfc, tid, isf32);
    if (tid < H2) b2l[tid] = ldf(b2, tid, isf32);
    if (tid < 2) bfl[tid] = ldf(bfc, tid, isf32);
    __syncthreads();

    const int r = tid & 7;
    const int node = blockIdx.x * 32 + (tid >> 3);   // 15625*32 == 500000

    float a0 = 0.f, a1 = 0.f;
    const int beg = off[node], end = off[node + 1];
    int j = beg;
    for (; j + 4 <= end; j += 4) {
        int s0 = csr[j], s1 = csr[j + 1], s2 = csr[j + 2], s3 = csr[j + 3];
        unsigned u0 = y2b[(size_t)s0 * 8 + r];
        unsigned u1 = y2b[(size_t)s1 * 8 + r];
        unsigned u2 = y2b[(size_t)s2 * 8 + r];
        unsigned u3 = y2b[(size_t)s3 * 8 + r];
        a0 += __uint_as_float(u0 << 16) + __uint_as_float(u1 << 16)
            + __uint_as_float(u2 << 16) + __uint_as_float(u3 << 16);
        a1 += __uint_as_float(u0 & 0xffff0000u) + __uint_as_float(u1 & 0xffff0000u)
            + __uint_as_float(u2 & 0xffff0000u) + __uint_as_float(u3 & 0xffff0000u);
    }
    for (; j < end; ++j) {
        unsigned u = y2b[(size_t)csr[j] * 8 + r];
        a0 += __uint_as_float(u << 16);
        a1 += __uint_as_float(u & 0xffff0000u);
    }
    float sc = dinv[node];
    unsigned su = y2b[(size_t)node * 8 + r];
    a0 += __uint_as_float(su << 16);
    a1 += __uint_as_float(su & 0xffff0000u);
    float h0 = sc * a0 + b2l[2 * r];
    float h1 = sc * a1 + b2l[2 * r + 1];
    h0 = h0 > 0.f ? h0 : 0.f;
    h1 = h1 > 0.f ? h1 : 0.f;
    float l0 = h0 * wl[4 * r]     + h1 * wl[4 * r + 2];
    float l1 = h0 * wl[4 * r + 1] + h1 * wl[4 * r + 3];
#pragma unroll
    for (int o = 4; o >= 1; o >>= 1) {
        l0 += __shfl_xor(l0, o, 8);
        l1 += __shfl_xor(l1, o, 8);
    }
    if (r == 0) {
        l0 += bfl[0];
        l1 += bfl[1];
        float mx = fmaxf(l0, l1);
        float lse = mx + logf(__expf(l0 - mx) + __expf(l1 - mx));
        if (isf32) {
            reinterpret_cast<float2*>(out)[node] = make_float2(l0 - lse, l1 - lse);
        } else {
            reinterpret_cast<unsigned*>(out)[node] =
                (unsigned)f2bf(l0 - lse) | ((unsigned)f2bf(l1 - lse) << 16);
        }
    }
}

extern "C" void kernel_launch(void* const* d_in, const int* in_sizes, int n_in,
                              void* d_out, int out_size, void* d_ws, size_t ws_size,
                              hipStream_t stream) {
    const void* x   = d_in[0];
    const int*  ei  = (const int*)d_in[1];
    const void* w1  = d_in[2];
    const void* b1  = d_in[3];
    const void* w2  = d_in[4];
    const void* b2  = d_in[5];
    const void* wfc = d_in[6];
    const void* bfc = d_in[7];
    const int* src = ei;
    const int* dst = ei + N_EDGES;

    // workspace (4B units), ~115 MB:
    // flag@0 | chist@64(256) | fbase@320(256) | acur@576(256) | dinv@832(501760)
    // cnt@502592(501760) | off@1004352(501761) | cur@1506176(501760)
    // ebufA@2007936(8M) | csr@10007936(8M) | y1b@18007936(8003584) | y2b@26011520(4001792)
    float*    ws    = (float*)d_ws;
    int*      flag  = (int*)ws;
    int*      chist = (int*)(ws + 64);
    int*      fbase = (int*)(ws + 320);
    int*      acur  = (int*)(ws + 576);
    float*    dinv  = ws + 832;
    int*      cnt   = (int*)(ws + 502592);
    int*      off   = (int*)(ws + 1004352);
    int*      cur   = (int*)(ws + 1506176);
    unsigned* ebufA = (unsigned*)(ws + 2007936);
    int*      csr   = (int*)(ws + 10007936);
    unsigned* y1b   = (unsigned*)(ws + 18007936);
    unsigned* y2b   = (unsigned*)(ws + 26011520);

    k_sniff<<<1, 64, 0, stream>>>((const unsigned int*)x, flag);
    hipMemsetAsync(chist, 0, 256 * sizeof(int), stream);
    hipMemsetAsync(cnt, 0, (size_t)501760 * sizeof(int), stream);
    k_bhist<<<256, 256, 0, stream>>>(dst, chist);
    k_scanc<<<1, 256, 0, stream>>>(chist, fbase, acur);
    k_scatA<<<977, 256, 0, stream>>>(src, dst, acur, ebufA);
    k_cntL2<<<NC * 4, 256, 0, stream>>>(ebufA, fbase, cnt);
    k_scanb<<<NC, 256, 0, stream>>>(cnt, fbase, off, cur, dinv);
    k_fill2<<<NC * 4, 256, 0, stream>>>(ebufA, fbase, cur, csr);
    k_gemm1<<<NFINE, 256, 0, stream>>>(x, w1, dinv, y1b, flag);
    k_pull1<<<31250, 256, 0, stream>>>(off, csr, y1b, dinv, b1, w2, y2b, flag);
    k_pull2<<<15625, 256, 0, stream>>>(off, csr, y2b, dinv, b2, wfc, bfc, d_out, flag);
}